// Round 1
// baseline (205.648 us; speedup 1.0000x reference)
//
#include <hip/hip_runtime.h>

#define LN_EPS 1e-5f

// ---------------------------------------------------------------------------
// Wavelet linear layer: h_out[b][o] = sum_i psi((x[b][i]-t[o][i])/scale[o][i]) * w[o][i]
// scale = 0.01 + 9.99*sigmoid(s) + 1e-8 ; psi(u) = (1-u^2)*exp(-0.5 u^2)
// One block per output o. BLOCK threads split i (float4-vectorized).
// Each thread holds 32 accumulators (one per batch row) so per-(o,i) scale
// math amortizes over all 32 batches and each param element is read once.
// ---------------------------------------------------------------------------
template<int KIN, int BLOCK>
__global__ __launch_bounds__(BLOCK)
void wav_layer(const float* __restrict__ xin, const float* __restrict__ w,
               const float* __restrict__ t, const float* __restrict__ s,
               float* __restrict__ hout)
{
    constexpr int K4 = KIN / 4;
    const int o   = blockIdx.x;
    const int tid = threadIdx.x;

    const float4* __restrict__ x4 = (const float4*)xin;
    const float4* __restrict__ w4 = (const float4*)w + (size_t)o * K4;
    const float4* __restrict__ t4 = (const float4*)t + (size_t)o * K4;
    const float4* __restrict__ s4 = (const float4*)s + (size_t)o * K4;

    float acc[32];
#pragma unroll
    for (int b = 0; b < 32; ++b) acc[b] = 0.f;

    for (int i = tid; i < K4; i += BLOCK) {
        float4 wv = w4[i];
        float4 tv = t4[i];
        float4 sv = s4[i];
        float svv[4] = {sv.x, sv.y, sv.z, sv.w};
        float tvv[4] = {tv.x, tv.y, tv.z, tv.w};
        float wl[4]  = {wv.x, wv.y, wv.z, wv.w};
        float inv[4], ti[4];
#pragma unroll
        for (int j = 0; j < 4; ++j) {
            float sig   = __builtin_amdgcn_rcpf(1.f + __expf(-svv[j]));
            float scale = fmaf(9.99f, sig, 0.01f) + 1e-8f;
            inv[j] = __builtin_amdgcn_rcpf(scale);
            ti[j]  = tvv[j] * inv[j];
        }
#pragma unroll
        for (int b = 0; b < 32; ++b) {
            float4 xv = x4[(size_t)b * K4 + i];
            float xc[4] = {xv.x, xv.y, xv.z, xv.w};
#pragma unroll
            for (int j = 0; j < 4; ++j) {
                float u  = fmaf(xc[j], inv[j], -ti[j]);
                float u2 = u * u;
                float e  = __expf(-0.5f * u2);
                acc[b] = fmaf((1.f - u2) * e, wl[j], acc[b]);
            }
        }
    }

    // reduce 32 accumulators across BLOCK threads
    __shared__ float red[(BLOCK / 64) * 32];
    const int lane = tid & 63;
    const int wid  = tid >> 6;
#pragma unroll
    for (int b = 0; b < 32; ++b) {
        float v = acc[b];
#pragma unroll
        for (int off = 32; off; off >>= 1) v += __shfl_down(v, off);
        if (lane == 0) red[wid * 32 + b] = v;
    }
    __syncthreads();
    if (tid < 32) {
        float v = 0.f;
#pragma unroll
        for (int k = 0; k < BLOCK / 64; ++k) v += red[k * 32 + tid];
        hout[tid * 512 + o] = v;   // h_out is (32, 512)
    }
}

// ---------------------------------------------------------------------------
// silu + LayerNorm over last dim (512). One block per batch row, 512 threads.
// var computed as E[a^2]-m^2 (single fused reduction pass).
// ---------------------------------------------------------------------------
__global__ __launch_bounds__(512)
void silu_ln(const float* __restrict__ hpre, const float* __restrict__ g,
             const float* __restrict__ bias, float* __restrict__ hout)
{
    const int b   = blockIdx.x;
    const int tid = threadIdx.x;
    float v = hpre[b * 512 + tid];
    float a = v * __builtin_amdgcn_rcpf(1.f + __expf(-v));   // silu

    float s1 = a, s2 = a * a;
#pragma unroll
    for (int off = 32; off; off >>= 1) {
        s1 += __shfl_down(s1, off);
        s2 += __shfl_down(s2, off);
    }
    __shared__ float r1[8], r2[8];
    const int lane = tid & 63, wid = tid >> 6;
    if (lane == 0) { r1[wid] = s1; r2[wid] = s2; }
    __syncthreads();
    float t1 = 0.f, t2 = 0.f;
#pragma unroll
    for (int k = 0; k < 8; ++k) { t1 += r1[k]; t2 += r2[k]; }
    float m   = t1 * (1.f / 512.f);
    float var = t2 * (1.f / 512.f) - m * m;
    float r   = __builtin_amdgcn_rsqf(var + LN_EPS);
    hout[b * 512 + tid] = (a - m) * r * g[tid] + bias[tid];
}

// ---------------------------------------------------------------------------
// Final classifier: out[b][c] = sum_i h[b][i]*cw[c][i] + cb[c]   (C=5, H=512)
// One block (one wave) per batch row.
// ---------------------------------------------------------------------------
__global__ __launch_bounds__(64)
void classifier(const float* __restrict__ h, const float* __restrict__ cw,
                const float* __restrict__ cb, float* __restrict__ out)
{
    const int b = blockIdx.x, lane = threadIdx.x;
    float acc[5] = {0.f, 0.f, 0.f, 0.f, 0.f};
    for (int i = lane; i < 512; i += 64) {
        float hv = h[b * 512 + i];
#pragma unroll
        for (int c = 0; c < 5; ++c) acc[c] = fmaf(hv, cw[c * 512 + i], acc[c]);
    }
#pragma unroll
    for (int c = 0; c < 5; ++c) {
        float v = acc[c];
#pragma unroll
        for (int off = 32; off; off >>= 1) v += __shfl_down(v, off);
        if (lane == 0) out[b * 5 + c] = v + cb[c];
    }
}

extern "C" void kernel_launch(void* const* d_in, const int* in_sizes, int n_in,
                              void* d_out, int out_size, void* d_ws, size_t ws_size,
                              hipStream_t stream)
{
    const float* x  = (const float*)d_in[0];
    const float* w0 = (const float*)d_in[1];
    const float* t0 = (const float*)d_in[2];
    const float* s0 = (const float*)d_in[3];
    const float* g0 = (const float*)d_in[4];
    const float* b0 = (const float*)d_in[5];
    const float* w1 = (const float*)d_in[6];
    const float* t1 = (const float*)d_in[7];
    const float* s1 = (const float*)d_in[8];
    const float* g1 = (const float*)d_in[9];
    const float* b1 = (const float*)d_in[10];
    const float* w2 = (const float*)d_in[11];
    const float* t2 = (const float*)d_in[12];
    const float* s2 = (const float*)d_in[13];
    const float* g2 = (const float*)d_in[14];
    const float* b2 = (const float*)d_in[15];
    const float* cw = (const float*)d_in[16];
    const float* cb = (const float*)d_in[17];
    float* out = (float*)d_out;

    float* bufA = (float*)d_ws;          // 32*512 floats = 64 KB
    float* bufB = bufA + 32 * 512;

    wav_layer<6144, 256><<<512, 256, 0, stream>>>(x,    w0, t0, s0, bufA);
    silu_ln<<<32, 512, 0, stream>>>(bufA, g0, b0, bufB);
    wav_layer<512, 128><<<512, 128, 0, stream>>>(bufB, w1, t1, s1, bufA);
    silu_ln<<<32, 512, 0, stream>>>(bufA, g1, b1, bufB);
    wav_layer<512, 128><<<512, 128, 0, stream>>>(bufB, w2, t2, s2, bufA);
    silu_ln<<<32, 512, 0, stream>>>(bufA, g2, b2, bufB);
    classifier<<<32, 64, 0, stream>>>(bufB, cw, cb, out);
}

// Round 2
// 204.027 us; speedup vs baseline: 1.0079x; 1.0079x over previous
//
#include <hip/hip_runtime.h>

#define LN_EPS 1e-5f
#define LOG2E 1.44269504f
#define NHALF_LOG2E (-0.72134752f)

#if __has_builtin(__builtin_amdgcn_exp2f)
#define EXP2F(x) __builtin_amdgcn_exp2f(x)
#else
#define EXP2F(x) __expf((x) * 0.69314718f)
#endif

// ---------------------------------------------------------------------------
// Transpose x (32 x KIN) -> xT (KIN x 32) so each wav thread's batch-block is
// 512 contiguous bytes. idx = i*32 + b; writes coalesced.
// ---------------------------------------------------------------------------
template<int KIN>
__global__ __launch_bounds__(256)
void transpose_x(const float* __restrict__ x, float* __restrict__ xT)
{
    int idx = blockIdx.x * 256 + threadIdx.x;
    int i = idx >> 5, b = idx & 31;
    xT[idx] = x[b * KIN + i];
}

// ---------------------------------------------------------------------------
// Wavelet linear, split-K. Block (o, si) covers CHUNK=K4/S float4-groups of i.
// Each thread: 1 float4 of params + 32 contiguous float4 of xT (512 B),
// 32 batch accumulators. Partial written to part[si][b][o].
// Per element: fma(u), mul(u2), mul(arg), v_exp, fma(pw), fma(acc).
// ---------------------------------------------------------------------------
template<int KIN, int BLOCK, int S>
__global__ __launch_bounds__(BLOCK, 4)
void wav_layer(const float* __restrict__ xT, const float* __restrict__ w,
               const float* __restrict__ t, const float* __restrict__ s,
               float* __restrict__ part)
{
    constexpr int K4 = KIN / 4;
    constexpr int CHUNK = K4 / S;
    const int o   = blockIdx.x;
    const int si  = blockIdx.y;
    const int tid = threadIdx.x;

    const float4* __restrict__ w4 = (const float4*)w + (size_t)o * K4;
    const float4* __restrict__ t4 = (const float4*)t + (size_t)o * K4;
    const float4* __restrict__ s4 = (const float4*)s + (size_t)o * K4;
    const float4* __restrict__ x4 = (const float4*)xT;

    float acc[32];
#pragma unroll
    for (int b = 0; b < 32; ++b) acc[b] = 0.f;

    for (int i4 = si * CHUNK + tid; i4 < (si + 1) * CHUNK; i4 += BLOCK) {
        float4 wv = w4[i4], tv = t4[i4], sv = s4[i4];
        float wa[4] = {wv.x, wv.y, wv.z, wv.w};
        float ta[4] = {tv.x, tv.y, tv.z, tv.w};
        float sa[4] = {sv.x, sv.y, sv.z, sv.w};
        const float4* __restrict__ xr = x4 + (size_t)i4 * 32;  // 4 rows x 8 float4
#pragma unroll
        for (int j = 0; j < 4; ++j) {
            float sig = __builtin_amdgcn_rcpf(1.f + EXP2F(-sa[j] * LOG2E));
            float inv = __builtin_amdgcn_rcpf(fmaf(9.99f, sig, 0.01000001f));
            float nti = -ta[j] * inv;
            float wj  = wa[j];
#pragma unroll
            for (int b4 = 0; b4 < 8; ++b4) {
                float4 xv = xr[j * 8 + b4];
                float xa[4] = {xv.x, xv.y, xv.z, xv.w};
#pragma unroll
                for (int k = 0; k < 4; ++k) {
                    float u  = fmaf(xa[k], inv, nti);
                    float u2 = u * u;
                    float e  = EXP2F(u2 * NHALF_LOG2E);
                    float pw = fmaf(-wj, u2, wj);          // w*(1-u2)
                    acc[b4 * 4 + k] = fmaf(pw, e, acc[b4 * 4 + k]);
                }
            }
        }
    }

    __shared__ float red[(BLOCK / 64) * 32];
    const int lane = tid & 63, wid = tid >> 6;
#pragma unroll
    for (int b = 0; b < 32; ++b) {
        float v = acc[b];
#pragma unroll
        for (int off = 32; off; off >>= 1) v += __shfl_down(v, off);
        if (lane == 0) red[wid * 32 + b] = v;
    }
    __syncthreads();
    if (tid < 32) {
        float v = 0.f;
#pragma unroll
        for (int k = 0; k < BLOCK / 64; ++k) v += red[k * 32 + tid];
        part[(size_t)si * 16384 + tid * 512 + o] = v;
    }
}

// ---------------------------------------------------------------------------
// Sum S partial slices + silu + LayerNorm(512). Block = batch row.
// Writes hT transposed (o-major) for the next wav layer.
// ---------------------------------------------------------------------------
template<int S>
__global__ __launch_bounds__(512)
void silu_ln(const float* __restrict__ part, const float* __restrict__ g,
             const float* __restrict__ bias, float* __restrict__ hT)
{
    const int b = blockIdx.x, tid = threadIdx.x;
    float v = 0.f;
#pragma unroll
    for (int si = 0; si < S; ++si) v += part[(size_t)si * 16384 + b * 512 + tid];
    float a = v * __builtin_amdgcn_rcpf(1.f + EXP2F(-v * LOG2E));  // silu

    float s1 = a, s2 = a * a;
#pragma unroll
    for (int off = 32; off; off >>= 1) {
        s1 += __shfl_down(s1, off);
        s2 += __shfl_down(s2, off);
    }
    __shared__ float r1[8], r2[8];
    const int lane = tid & 63, wid = tid >> 6;
    if (lane == 0) { r1[wid] = s1; r2[wid] = s2; }
    __syncthreads();
    float t1 = 0.f, t2 = 0.f;
#pragma unroll
    for (int k = 0; k < 8; ++k) { t1 += r1[k]; t2 += r2[k]; }
    float m   = t1 * (1.f / 512.f);
    float var = t2 * (1.f / 512.f) - m * m;
    float r   = __builtin_amdgcn_rsqf(var + LN_EPS);
    hT[tid * 32 + b] = (a - m) * r * g[tid] + bias[tid];
}

// ---------------------------------------------------------------------------
// Final: sum partials + silu + LN + classifier (out = hln @ cw.T + cb).
// ---------------------------------------------------------------------------
template<int S>
__global__ __launch_bounds__(512)
void silu_ln_cls(const float* __restrict__ part, const float* __restrict__ g,
                 const float* __restrict__ bias, const float* __restrict__ cw,
                 const float* __restrict__ cb, float* __restrict__ out)
{
    const int b = blockIdx.x, tid = threadIdx.x;
    float v = 0.f;
#pragma unroll
    for (int si = 0; si < S; ++si) v += part[(size_t)si * 16384 + b * 512 + tid];
    float a = v * __builtin_amdgcn_rcpf(1.f + EXP2F(-v * LOG2E));

    float s1 = a, s2 = a * a;
#pragma unroll
    for (int off = 32; off; off >>= 1) {
        s1 += __shfl_down(s1, off);
        s2 += __shfl_down(s2, off);
    }
    __shared__ float r1[8], r2[8];
    const int lane = tid & 63, wid = tid >> 6;
    if (lane == 0) { r1[wid] = s1; r2[wid] = s2; }
    __syncthreads();
    float t1 = 0.f, t2 = 0.f;
#pragma unroll
    for (int k = 0; k < 8; ++k) { t1 += r1[k]; t2 += r2[k]; }
    float m   = t1 * (1.f / 512.f);
    float var = t2 * (1.f / 512.f) - m * m;
    float r   = __builtin_amdgcn_rsqf(var + LN_EPS);
    float hl  = (a - m) * r * g[tid] + bias[tid];

    __shared__ float cr[5][8];
#pragma unroll
    for (int c = 0; c < 5; ++c) {
        float pv = hl * cw[c * 512 + tid];
#pragma unroll
        for (int off = 32; off; off >>= 1) pv += __shfl_down(pv, off);
        if (lane == 0) cr[c][wid] = pv;
    }
    __syncthreads();
    if (tid < 5) {
        float sum = 0.f;
#pragma unroll
        for (int k = 0; k < 8; ++k) sum += cr[tid][k];
        out[b * 5 + tid] = sum + cb[tid];
    }
}

extern "C" void kernel_launch(void* const* d_in, const int* in_sizes, int n_in,
                              void* d_out, int out_size, void* d_ws, size_t ws_size,
                              hipStream_t stream)
{
    const float* x  = (const float*)d_in[0];
    const float* w0 = (const float*)d_in[1];
    const float* t0 = (const float*)d_in[2];
    const float* s0 = (const float*)d_in[3];
    const float* g0 = (const float*)d_in[4];
    const float* b0 = (const float*)d_in[5];
    const float* w1 = (const float*)d_in[6];
    const float* t1 = (const float*)d_in[7];
    const float* s1 = (const float*)d_in[8];
    const float* g1 = (const float*)d_in[9];
    const float* b1 = (const float*)d_in[10];
    const float* w2 = (const float*)d_in[11];
    const float* t2 = (const float*)d_in[12];
    const float* s2 = (const float*)d_in[13];
    const float* g2 = (const float*)d_in[14];
    const float* b2 = (const float*)d_in[15];
    const float* cw = (const float*)d_in[16];
    const float* cb = (const float*)d_in[17];
    float* out = (float*)d_out;

    // ws layout (floats): xT 196608 | part 6*16384 | hT 16384  (~1.19 MB)
    float* xT   = (float*)d_ws;
    float* part = xT + 196608;
    float* hT   = part + 6 * 16384;

    transpose_x<6144><<<768, 256, 0, stream>>>(x, xT);
    wav_layer<6144, 256, 6><<<dim3(512, 6), 256, 0, stream>>>(xT, w0, t0, s0, part);
    silu_ln<6><<<32, 512, 0, stream>>>(part, g0, b0, hT);
    wav_layer<512, 128, 1><<<dim3(512, 1), 128, 0, stream>>>(hT, w1, t1, s1, part);
    silu_ln<1><<<32, 512, 0, stream>>>(part, g1, b1, hT);
    wav_layer<512, 128, 1><<<dim3(512, 1), 128, 0, stream>>>(hT, w2, t2, s2, part);
    silu_ln_cls<1><<<32, 512, 0, stream>>>(part, g2, b2, cw, cb, out);
}

// Round 3
// 175.141 us; speedup vs baseline: 1.1742x; 1.1649x over previous
//
#include <hip/hip_runtime.h>

#define LN_EPS 1e-5f
#define LOG2E 1.44269504f
#define NHALF_LOG2E (-0.72134752f)

#if __has_builtin(__builtin_amdgcn_exp2f)
#define EXP2F(x) __builtin_amdgcn_exp2f(x)
#else
#define EXP2F(x) __expf((x) * 0.69314718f)
#endif

// ---------------------------------------------------------------------------
// Transpose x (32 x KIN) -> xT (KIN x 32). idx = i*32 + b; writes coalesced.
// ---------------------------------------------------------------------------
template<int KIN>
__global__ __launch_bounds__(256)
void transpose_x(const float* __restrict__ x, float* __restrict__ xT)
{
    int idx = blockIdx.x * 256 + threadIdx.x;
    int i = idx >> 5, b = idx & 31;
    xT[idx] = x[b * KIN + i];
}

// ---------------------------------------------------------------------------
// Wavelet linear, lane = (batch-pair, i-subgroup).
// Block = 128 threads = 2 waves; wave w owns output o = 2*blockIdx.x + w,
// i-range [si*RANGE, (si+1)*RANGE).
// Phase 1 (prep): wave computes {inv, -t*inv, w} per i of its range into its
//   own LDS region (one-time sigmoid/rcp chain, amortized over 32 batches).
// Phase 2 (main): lane (p = lane&15 -> batches 2p,2p+1; g = lane>>4 ->
//   i = base + 4*st + g). x load = float2/lane, 512 B contiguous per wave
//   instruction (L1-friendly, reused by all o). prep via ds_read_b128
//   broadcast (4 distinct addrs). 2 accumulators/lane.
// Epilogue: 2 shuffles (sum over g), lanes 0..15 store coalesced float2 to
//   part[si][o][b].
// ---------------------------------------------------------------------------
template<int KIN, int S>
__global__ __launch_bounds__(128, 6)
void wav_layer(const float* __restrict__ xT, const float* __restrict__ w,
               const float* __restrict__ t, const float* __restrict__ s,
               float* __restrict__ part)
{
    constexpr int RANGE = KIN / S;     // i-values per wave
    constexpr int STEPS = RANGE / 4;
    constexpr int PREPS = RANGE / 64;
    __shared__ float4 prep[2][RANGE];

    const int wave = threadIdx.x >> 6;
    const int lane = threadIdx.x & 63;
    const int o    = (blockIdx.x << 1) + wave;
    const int si   = blockIdx.y;
    const int ibase = si * RANGE;

    const float* __restrict__ wp = w + (size_t)o * KIN + ibase;
    const float* __restrict__ tp = t + (size_t)o * KIN + ibase;
    const float* __restrict__ sp = s + (size_t)o * KIN + ibase;

#pragma unroll
    for (int r = 0; r < PREPS; ++r) {
        int il = r * 64 + lane;
        float wv = wp[il], tv = tp[il], sv = sp[il];
        float sig = __builtin_amdgcn_rcpf(1.f + EXP2F(-sv * LOG2E));
        float inv = __builtin_amdgcn_rcpf(fmaf(9.99f, sig, 0.01000001f));
        prep[wave][il] = make_float4(inv, -tv * inv, wv, 0.f);
    }
    __syncthreads();

    const int p = lane & 15, g = lane >> 4;
    const float2* __restrict__ xp = (const float2*)xT + (size_t)(ibase + g) * 16 + p;

    float acc0 = 0.f, acc1 = 0.f;
#pragma unroll 4
    for (int st = 0; st < STEPS; ++st) {
        float4 pr = prep[wave][st * 4 + g];
        float2 xv = xp[(size_t)st * 64];
        float u0 = fmaf(xv.x, pr.x, pr.y);
        float u1 = fmaf(xv.y, pr.x, pr.y);
        float q0 = u0 * u0, q1 = u1 * u1;
        float e0 = EXP2F(q0 * NHALF_LOG2E);
        float e1 = EXP2F(q1 * NHALF_LOG2E);
        float pw0 = fmaf(-pr.z, q0, pr.z);
        float pw1 = fmaf(-pr.z, q1, pr.z);
        acc0 = fmaf(pw0, e0, acc0);
        acc1 = fmaf(pw1, e1, acc1);
    }

    // sum the 4 i-subgroups: lanes {p, p+16, p+32, p+48}
    acc0 += __shfl_down(acc0, 32); acc0 += __shfl_down(acc0, 16);
    acc1 += __shfl_down(acc1, 32); acc1 += __shfl_down(acc1, 16);
    if (lane < 16) {
        float2* pp = (float2*)(part + (size_t)si * 16384 + o * 32) + p;
        *pp = make_float2(acc0, acc1);
    }
}

// ---------------------------------------------------------------------------
// Sum S partial slices (part layout [si][o][b]) + silu + LayerNorm(512).
// Block = batch row b, tid = o. Writes hT[o][b] (input layout for next wav).
// ---------------------------------------------------------------------------
template<int S>
__global__ __launch_bounds__(512)
void silu_ln(const float* __restrict__ part, const float* __restrict__ g,
             const float* __restrict__ bias, float* __restrict__ hT)
{
    const int b = blockIdx.x, tid = threadIdx.x;
    float v = 0.f;
#pragma unroll
    for (int si = 0; si < S; ++si) v += part[(size_t)si * 16384 + tid * 32 + b];
    float a = v * __builtin_amdgcn_rcpf(1.f + EXP2F(-v * LOG2E));  // silu

    float s1 = a, s2 = a * a;
#pragma unroll
    for (int off = 32; off; off >>= 1) {
        s1 += __shfl_down(s1, off);
        s2 += __shfl_down(s2, off);
    }
    __shared__ float r1[8], r2[8];
    const int lane = tid & 63, wid = tid >> 6;
    if (lane == 0) { r1[wid] = s1; r2[wid] = s2; }
    __syncthreads();
    float t1 = 0.f, t2 = 0.f;
#pragma unroll
    for (int k = 0; k < 8; ++k) { t1 += r1[k]; t2 += r2[k]; }
    float m   = t1 * (1.f / 512.f);
    float var = t2 * (1.f / 512.f) - m * m;
    float r   = __builtin_amdgcn_rsqf(var + LN_EPS);
    hT[tid * 32 + b] = (a - m) * r * g[tid] + bias[tid];
}

// ---------------------------------------------------------------------------
// Final: sum partials + silu + LN + classifier (out = hln @ cw.T + cb).
// ---------------------------------------------------------------------------
template<int S>
__global__ __launch_bounds__(512)
void silu_ln_cls(const float* __restrict__ part, const float* __restrict__ g,
                 const float* __restrict__ bias, const float* __restrict__ cw,
                 const float* __restrict__ cb, float* __restrict__ out)
{
    const int b = blockIdx.x, tid = threadIdx.x;
    float v = 0.f;
#pragma unroll
    for (int si = 0; si < S; ++si) v += part[(size_t)si * 16384 + tid * 32 + b];
    float a = v * __builtin_amdgcn_rcpf(1.f + EXP2F(-v * LOG2E));

    float s1 = a, s2 = a * a;
#pragma unroll
    for (int off = 32; off; off >>= 1) {
        s1 += __shfl_down(s1, off);
        s2 += __shfl_down(s2, off);
    }
    __shared__ float r1[8], r2[8];
    const int lane = tid & 63, wid = tid >> 6;
    if (lane == 0) { r1[wid] = s1; r2[wid] = s2; }
    __syncthreads();
    float t1 = 0.f, t2 = 0.f;
#pragma unroll
    for (int k = 0; k < 8; ++k) { t1 += r1[k]; t2 += r2[k]; }
    float m   = t1 * (1.f / 512.f);
    float var = t2 * (1.f / 512.f) - m * m;
    float r   = __builtin_amdgcn_rsqf(var + LN_EPS);
    float hl  = (a - m) * r * g[tid] + bias[tid];

    __shared__ float cr[5][8];
#pragma unroll
    for (int c = 0; c < 5; ++c) {
        float pv = hl * cw[c * 512 + tid];
#pragma unroll
        for (int off = 32; off; off >>= 1) pv += __shfl_down(pv, off);
        if (lane == 0) cr[c][wid] = pv;
    }
    __syncthreads();
    if (tid < 5) {
        float sum = 0.f;
#pragma unroll
        for (int k = 0; k < 8; ++k) sum += cr[tid][k];
        out[b * 5 + tid] = sum + cb[tid];
    }
}

extern "C" void kernel_launch(void* const* d_in, const int* in_sizes, int n_in,
                              void* d_out, int out_size, void* d_ws, size_t ws_size,
                              hipStream_t stream)
{
    const float* x  = (const float*)d_in[0];
    const float* w0 = (const float*)d_in[1];
    const float* t0 = (const float*)d_in[2];
    const float* s0 = (const float*)d_in[3];
    const float* g0 = (const float*)d_in[4];
    const float* b0 = (const float*)d_in[5];
    const float* w1 = (const float*)d_in[6];
    const float* t1 = (const float*)d_in[7];
    const float* s1 = (const float*)d_in[8];
    const float* g1 = (const float*)d_in[9];
    const float* b1 = (const float*)d_in[10];
    const float* w2 = (const float*)d_in[11];
    const float* t2 = (const float*)d_in[12];
    const float* s2 = (const float*)d_in[13];
    const float* g2 = (const float*)d_in[14];
    const float* b2 = (const float*)d_in[15];
    const float* cw = (const float*)d_in[16];
    const float* cb = (const float*)d_in[17];
    float* out = (float*)d_out;

    // ws layout (floats): xT 196608 | part 16*16384 | hT 16384  (~1.86 MB)
    float* xT   = (float*)d_ws;
    float* part = xT + 196608;
    float* hT   = part + 16 * 16384;

    transpose_x<6144><<<768, 256, 0, stream>>>(x, xT);
    wav_layer<6144, 16><<<dim3(256, 16), 128, 0, stream>>>(xT, w0, t0, s0, part);
    silu_ln<16><<<32, 512, 0, stream>>>(part, g0, b0, hT);
    wav_layer<512, 8><<<dim3(256, 8), 128, 0, stream>>>(hT, w1, t1, s1, part);
    silu_ln<8><<<32, 512, 0, stream>>>(part, g1, b1, hT);
    wav_layer<512, 8><<<dim3(256, 8), 128, 0, stream>>>(hT, w2, t2, s2, part);
    silu_ln_cls<8><<<32, 512, 0, stream>>>(part, g2, b2, cw, cb, out);
}

// Round 4
// 167.698 us; speedup vs baseline: 1.2263x; 1.0444x over previous
//
#include <hip/hip_runtime.h>

#define LN_EPS 1e-5f
#define LOG2E 1.44269504f
#define NHALF_LOG2E (-0.72134752f)

#if __has_builtin(__builtin_amdgcn_exp2f)
#define EXP2F(x) __builtin_amdgcn_exp2f(x)
#else
#define EXP2F(x) __expf((x) * 0.69314718f)
#endif

// ---------------------------------------------------------------------------
// Transpose x (32 x KIN) -> xT (KIN x 32). idx = i*32 + b; writes coalesced.
// ---------------------------------------------------------------------------
template<int KIN>
__global__ __launch_bounds__(256)
void transpose_x(const float* __restrict__ x, float* __restrict__ xT)
{
    int idx = blockIdx.x * 256 + threadIdx.x;
    int i = idx >> 5, b = idx & 31;
    xT[idx] = x[b * KIN + i];
}

// ---------------------------------------------------------------------------
// Wavelet linear, lane = (batch-pair, i-subgroup). Block = 2 waves; wave w
// owns o = 2*blockIdx.x + w, i-range [si*RANGE, (si+1)*RANGE).
// prep (per-wave LDS): {inv, -t*inv} float2 + w float, computed once.
// Main loop: lane p=lane&15 -> batches 2p,2p+1; g=lane>>4 -> i = 4*st+g.
// x load float2/lane = 512 B contiguous per wave instr; prep via broadcast
// LDS reads (4 distinct addrs). Unroll 8 -> 8 global loads in flight/wave.
// Epilogue: 2 shuffles, lanes 0..15 store coalesced float2 to part[si][o][b].
// ---------------------------------------------------------------------------
template<int KIN, int S>
__global__ __launch_bounds__(128, 6)
void wav_layer(const float* __restrict__ xT, const float* __restrict__ w,
               const float* __restrict__ t, const float* __restrict__ s,
               float* __restrict__ part)
{
    constexpr int RANGE = KIN / S;     // i-values per wave
    constexpr int STEPS = RANGE / 4;
    constexpr int PREPS = RANGE / 64;
    __shared__ float2 prepA[2][RANGE];  // {inv, -t*inv}
    __shared__ float  prepW[2][RANGE];  // w

    const int wave = threadIdx.x >> 6;
    const int lane = threadIdx.x & 63;
    const int o    = (blockIdx.x << 1) + wave;
    const int si   = blockIdx.y;
    const int ibase = si * RANGE;

    const float* __restrict__ wp = w + (size_t)o * KIN + ibase;
    const float* __restrict__ tp = t + (size_t)o * KIN + ibase;
    const float* __restrict__ sp = s + (size_t)o * KIN + ibase;

#pragma unroll
    for (int r = 0; r < PREPS; ++r) {
        int il = r * 64 + lane;
        float wv = wp[il], tv = tp[il], sv = sp[il];
        float sig = __builtin_amdgcn_rcpf(1.f + EXP2F(-sv * LOG2E));
        float inv = __builtin_amdgcn_rcpf(fmaf(9.99f, sig, 0.01000001f));
        prepA[wave][il] = make_float2(inv, -tv * inv);
        prepW[wave][il] = wv;
    }
    __syncthreads();

    const int p = lane & 15, g = lane >> 4;
    const float2* __restrict__ xp = (const float2*)xT + (size_t)(ibase + g) * 16 + p;

    float acc0 = 0.f, acc1 = 0.f;
#pragma unroll 8
    for (int st = 0; st < STEPS; ++st) {
        float2 pr = prepA[wave][st * 4 + g];
        float  wj = prepW[wave][st * 4 + g];
        float2 xv = xp[(size_t)st * 64];
        float u0 = fmaf(xv.x, pr.x, pr.y);
        float u1 = fmaf(xv.y, pr.x, pr.y);
        float q0 = u0 * u0, q1 = u1 * u1;
        float e0 = EXP2F(q0 * NHALF_LOG2E);
        float e1 = EXP2F(q1 * NHALF_LOG2E);
        float pw0 = fmaf(-wj, q0, wj);
        float pw1 = fmaf(-wj, q1, wj);
        acc0 = fmaf(pw0, e0, acc0);
        acc1 = fmaf(pw1, e1, acc1);
    }

    // sum the 4 i-subgroups: lanes {p, p+16, p+32, p+48}
    acc0 += __shfl_down(acc0, 32); acc0 += __shfl_down(acc0, 16);
    acc1 += __shfl_down(acc1, 32); acc1 += __shfl_down(acc1, 16);
    if (lane < 16) {
        float2* pp = (float2*)(part + (size_t)si * 16384 + o * 32) + p;
        *pp = make_float2(acc0, acc1);
    }
}

// ---------------------------------------------------------------------------
// Sum S partial slices (part layout [si][o][b]) + silu + LayerNorm(512).
// Block = batch row b, tid = o. Writes hT[o][b] (input layout for next wav).
// ---------------------------------------------------------------------------
template<int S>
__global__ __launch_bounds__(512)
void silu_ln(const float* __restrict__ part, const float* __restrict__ g,
             const float* __restrict__ bias, float* __restrict__ hT)
{
    const int b = blockIdx.x, tid = threadIdx.x;
    float v = 0.f;
#pragma unroll
    for (int si = 0; si < S; ++si) v += part[(size_t)si * 16384 + tid * 32 + b];
    float a = v * __builtin_amdgcn_rcpf(1.f + EXP2F(-v * LOG2E));  // silu

    float s1 = a, s2 = a * a;
#pragma unroll
    for (int off = 32; off; off >>= 1) {
        s1 += __shfl_down(s1, off);
        s2 += __shfl_down(s2, off);
    }
    __shared__ float r1[8], r2[8];
    const int lane = tid & 63, wid = tid >> 6;
    if (lane == 0) { r1[wid] = s1; r2[wid] = s2; }
    __syncthreads();
    float t1 = 0.f, t2 = 0.f;
#pragma unroll
    for (int k = 0; k < 8; ++k) { t1 += r1[k]; t2 += r2[k]; }
    float m   = t1 * (1.f / 512.f);
    float var = t2 * (1.f / 512.f) - m * m;
    float r   = __builtin_amdgcn_rsqf(var + LN_EPS);
    hT[tid * 32 + b] = (a - m) * r * g[tid] + bias[tid];
}

// ---------------------------------------------------------------------------
// Final: sum partials + silu + LN + classifier (out = hln @ cw.T + cb).
// ---------------------------------------------------------------------------
template<int S>
__global__ __launch_bounds__(512)
void silu_ln_cls(const float* __restrict__ part, const float* __restrict__ g,
                 const float* __restrict__ bias, const float* __restrict__ cw,
                 const float* __restrict__ cb, float* __restrict__ out)
{
    const int b = blockIdx.x, tid = threadIdx.x;
    float v = 0.f;
#pragma unroll
    for (int si = 0; si < S; ++si) v += part[(size_t)si * 16384 + tid * 32 + b];
    float a = v * __builtin_amdgcn_rcpf(1.f + EXP2F(-v * LOG2E));

    float s1 = a, s2 = a * a;
#pragma unroll
    for (int off = 32; off; off >>= 1) {
        s1 += __shfl_down(s1, off);
        s2 += __shfl_down(s2, off);
    }
    __shared__ float r1[8], r2[8];
    const int lane = tid & 63, wid = tid >> 6;
    if (lane == 0) { r1[wid] = s1; r2[wid] = s2; }
    __syncthreads();
    float t1 = 0.f, t2 = 0.f;
#pragma unroll
    for (int k = 0; k < 8; ++k) { t1 += r1[k]; t2 += r2[k]; }
    float m   = t1 * (1.f / 512.f);
    float var = t2 * (1.f / 512.f) - m * m;
    float r   = __builtin_amdgcn_rsqf(var + LN_EPS);
    float hl  = (a - m) * r * g[tid] + bias[tid];

    __shared__ float cr[5][8];
#pragma unroll
    for (int c = 0; c < 5; ++c) {
        float pv = hl * cw[c * 512 + tid];
#pragma unroll
        for (int off = 32; off; off >>= 1) pv += __shfl_down(pv, off);
        if (lane == 0) cr[c][wid] = pv;
    }
    __syncthreads();
    if (tid < 5) {
        float sum = 0.f;
#pragma unroll
        for (int k = 0; k < 8; ++k) sum += cr[tid][k];
        out[b * 5 + tid] = sum + cb[tid];
    }
}

extern "C" void kernel_launch(void* const* d_in, const int* in_sizes, int n_in,
                              void* d_out, int out_size, void* d_ws, size_t ws_size,
                              hipStream_t stream)
{
    const float* x  = (const float*)d_in[0];
    const float* w0 = (const float*)d_in[1];
    const float* t0 = (const float*)d_in[2];
    const float* s0 = (const float*)d_in[3];
    const float* g0 = (const float*)d_in[4];
    const float* b0 = (const float*)d_in[5];
    const float* w1 = (const float*)d_in[6];
    const float* t1 = (const float*)d_in[7];
    const float* s1 = (const float*)d_in[8];
    const float* g1 = (const float*)d_in[9];
    const float* b1 = (const float*)d_in[10];
    const float* w2 = (const float*)d_in[11];
    const float* t2 = (const float*)d_in[12];
    const float* s2 = (const float*)d_in[13];
    const float* g2 = (const float*)d_in[14];
    const float* b2 = (const float*)d_in[15];
    const float* cw = (const float*)d_in[16];
    const float* cb = (const float*)d_in[17];
    float* out = (float*)d_out;

    // ws layout (floats): xT 196608 | part 16*16384 | hT 16384  (~1.86 MB)
    float* xT   = (float*)d_ws;
    float* part = xT + 196608;
    float* hT   = part + 16 * 16384;

    transpose_x<6144><<<768, 256, 0, stream>>>(x, xT);
    wav_layer<6144, 16><<<dim3(256, 16), 128, 0, stream>>>(xT, w0, t0, s0, part);
    silu_ln<16><<<32, 512, 0, stream>>>(part, g0, b0, hT);
    wav_layer<512, 8><<<dim3(256, 8), 128, 0, stream>>>(hT, w1, t1, s1, part);
    silu_ln<8><<<32, 512, 0, stream>>>(part, g1, b1, hT);
    wav_layer<512, 8><<<dim3(256, 8), 128, 0, stream>>>(hT, w2, t2, s2, part);
    silu_ln_cls<8><<<32, 512, 0, stream>>>(part, g2, b2, cw, cb, out);
}